// Round 2
// baseline (62.712 us; speedup 1.0000x reference)
//
#include <hip/hip_runtime.h>
#include <hip/hip_bf16.h>

typedef __bf16 bf16;
typedef __bf16 bf16x8 __attribute__((ext_vector_type(8)));
typedef __bf16 bf16x4 __attribute__((ext_vector_type(4)));
typedef float  f32x4  __attribute__((ext_vector_type(4)));

#define KDIM 512
#define MDIM 64
#define TDIM 4096
#define BN   128
#define BK   64
#define NTILE (TDIM / BN)   // 32 tiles per batch
#define KITER (KDIM / BK)   // 8

// LDS byte layout
#define SA_OFF   0        // text tile  [64][64]  bf16, swizzled: 8192 B
#define SB_OFF   8192     // audio tile [128][64] bf16, swizzled: 16384 B
#define INVT_OFF 24576    // 64 floats
#define INVA_OFF 24832    // 128 floats
#define LDS_BYTES 25344

__global__ __launch_bounds__(256, 2)
void expnegl2_fused_kernel(const float* __restrict__ audio,
                           const float* __restrict__ text,
                           float* __restrict__ out)
{
    __shared__ __attribute__((aligned(16))) unsigned char lds[LDS_BYTES];

    const int tid  = threadIdx.x;

    // T1: bijective XCD swizzle. HW round-robins linear block id % 8 across
    // XCDs; remap so XCD k owns a contiguous chunk of work = 4 full batches.
    // Text tile (131 KB/batch) then stays L2-resident per XCD instead of
    // being fetched by all 8 XCDs (saves ~29 MB HBM fetch).
    const int linear = blockIdx.x;
    const int cpx    = gridDim.x >> 3;            // 1024/8 = 128
    const int wg     = (linear & 7) * cpx + (linear >> 3);
    const int b      = wg / NTILE;
    const int t0     = (wg % NTILE) * BN;

    const int c4   = tid & 15;   // 16-byte column chunk within 64-col tile
    const int r0   = tid >> 4;   // 0..15 base row
    const int lane = tid & 63;
    const int wave = tid >> 6;

    const float* aBase = audio + ((size_t)b * TDIM + t0) * KDIM;
    const float* tBase = text  + (size_t)b * MDIM * KDIM;

    f32x4 acc[4][2];
    #pragma unroll
    for (int i = 0; i < 4; ++i)
        #pragma unroll
        for (int j = 0; j < 2; ++j)
            acc[i][j] = (f32x4){0.f, 0.f, 0.f, 0.f};

    float ssA[8], ssT[4];
    #pragma unroll
    for (int j = 0; j < 8; ++j) ssA[j] = 0.f;
    #pragma unroll
    for (int j = 0; j < 4; ++j) ssT[j] = 0.f;

    const int frow = lane & 15;  // MFMA fragment row/col within 16
    const int kgrp = lane >> 4;  // MFMA k-group (0..3)

    // T14 async-STAGE: prefetch registers. Loads for tile k+1 are issued
    // right after the store barrier so HBM latency hides under the MFMA
    // phase; the vmcnt wait lands at the next iteration's store.
    f32x4 pT[4], pA[8];

    auto load_tile = [&](int k0) {
        #pragma unroll
        for (int j = 0; j < 4; ++j)
            pT[j] = *reinterpret_cast<const f32x4*>(
                tBase + (size_t)(j * 16 + r0) * KDIM + k0 + c4 * 4);
        #pragma unroll
        for (int j = 0; j < 8; ++j)
            pA[j] = *reinterpret_cast<const f32x4*>(
                aBase + (size_t)(j * 16 + r0) * KDIM + k0 + c4 * 4);
    };

    auto store_tile = [&]() {
        #pragma unroll
        for (int j = 0; j < 4; ++j) {
            f32x4 v = pT[j];
            ssT[j] += v.x * v.x + v.y * v.y + v.z * v.z + v.w * v.w;
            bf16x4 q = { (bf16)v.x, (bf16)v.y, (bf16)v.z, (bf16)v.w };
            const int row = j * 16 + r0;
            const int off = SA_OFF + row * 128 + ((c4 * 8) ^ ((row & 7) << 4));
            *reinterpret_cast<unsigned long long*>(lds + off) =
                __builtin_bit_cast(unsigned long long, q);
        }
        #pragma unroll
        for (int j = 0; j < 8; ++j) {
            f32x4 v = pA[j];
            ssA[j] += v.x * v.x + v.y * v.y + v.z * v.z + v.w * v.w;
            bf16x4 q = { (bf16)v.x, (bf16)v.y, (bf16)v.z, (bf16)v.w };
            const int row = j * 16 + r0;
            const int off = SB_OFF + row * 128 + ((c4 * 8) ^ ((row & 7) << 4));
            *reinterpret_cast<unsigned long long*>(lds + off) =
                __builtin_bit_cast(unsigned long long, q);
        }
    };

    load_tile(0);

    for (int ki = 0; ki < KITER; ++ki) {
        store_tile();          // implicit vmcnt wait on pT/pA, sumsq, ->LDS
        __syncthreads();       // tile visible to all waves

        if (ki + 1 < KITER)
            load_tile((ki + 1) * BK);   // issue next tile's loads NOW

        // ---- MFMA: acc[mi][ni] += text_frag[mi] * audio_frag[ni] ----
        #pragma unroll
        for (int kk = 0; kk < 2; ++kk) {
            const int kbyte = kk * 64 + kgrp * 16;
            bf16x8 afrag[4], bfrag[2];
            #pragma unroll
            for (int mi = 0; mi < 4; ++mi) {
                const int row = mi * 16 + frow;
                afrag[mi] = *reinterpret_cast<const bf16x8*>(
                    lds + SA_OFF + row * 128 + (kbyte ^ ((row & 7) << 4)));
            }
            #pragma unroll
            for (int ni = 0; ni < 2; ++ni) {
                const int trow = wave * 32 + ni * 16 + frow;
                bfrag[ni] = *reinterpret_cast<const bf16x8*>(
                    lds + SB_OFF + trow * 128 + (kbyte ^ ((trow & 7) << 4)));
            }
            #pragma unroll
            for (int mi = 0; mi < 4; ++mi)
                #pragma unroll
                for (int ni = 0; ni < 2; ++ni)
                    asm volatile("v_mfma_f32_16x16x32_bf16 %0, %1, %2, %0"
                                 : "+v"(acc[mi][ni])
                                 : "v"(afrag[mi]), "v"(bfrag[ni]));
        }
        __syncthreads();       // all waves' ds_reads done -> LDS reusable
    }

    // ---- reduce sum-of-squares across the 16 lanes sharing a row ----
    #pragma unroll
    for (int j = 0; j < 4; ++j) {
        float s = ssT[j];
        s += __shfl_xor(s, 1); s += __shfl_xor(s, 2);
        s += __shfl_xor(s, 4); s += __shfl_xor(s, 8);
        ssT[j] = s;
    }
    #pragma unroll
    for (int j = 0; j < 8; ++j) {
        float s = ssA[j];
        s += __shfl_xor(s, 1); s += __shfl_xor(s, 2);
        s += __shfl_xor(s, 4); s += __shfl_xor(s, 8);
        ssA[j] = s;
    }
    float* invT = reinterpret_cast<float*>(lds + INVT_OFF);
    float* invA = reinterpret_cast<float*>(lds + INVA_OFF);
    if (c4 == 0) {
        #pragma unroll
        for (int j = 0; j < 4; ++j)
            invT[j * 16 + r0] = 1.f / fmaxf(sqrtf(ssT[j]), 1e-12f);
        #pragma unroll
        for (int j = 0; j < 8; ++j)
            invA[j * 16 + r0] = 1.f / fmaxf(sqrtf(ssA[j]), 1e-12f);
    }
    __syncthreads();

    // ---- epilogue: scale by inv-norms, exp(-sqrt(max(2-2*dot, eps))) ----
    // C/D layout (16x16x32): col = lane&15, row = (lane>>4)*4 + j  [m89]
    float* obase = out + (size_t)b * MDIM * TDIM + t0;
    #pragma unroll
    for (int ni = 0; ni < 2; ++ni) {
        const int cl = wave * 32 + ni * 16 + frow;   // local col in [0,128)
        const float iA = invA[cl];
        #pragma unroll
        for (int mi = 0; mi < 4; ++mi) {
            #pragma unroll
            for (int j = 0; j < 4; ++j) {
                const int m = mi * 16 + kgrp * 4 + j;
                const float dotn = acc[mi][ni][j] * invT[m] * iA;
                const float d2 = fmaxf(2.f - 2.f * dotn, 1e-12f);
                obase[(size_t)m * TDIM + cl] = __expf(-sqrtf(d2));
            }
        }
    }
}

extern "C" void kernel_launch(void* const* d_in, const int* in_sizes, int n_in,
                              void* d_out, int out_size, void* d_ws, size_t ws_size,
                              hipStream_t stream) {
    const float* audio = (const float*)d_in[0];
    const float* text  = (const float*)d_in[1];
    float* out = (float*)d_out;

    const int B = in_sizes[0] / (TDIM * KDIM);   // 32
    dim3 grid(B * NTILE);                         // 1024, %8 == 0 (bijective swizzle ok)
    expnegl2_fused_kernel<<<grid, 256, 0, stream>>>(audio, text, out);
}

// Round 3
// 58.970 us; speedup vs baseline: 1.0635x; 1.0635x over previous
//
#include <hip/hip_runtime.h>
#include <hip/hip_bf16.h>

typedef __bf16 bf16;
typedef __bf16 bf16x8 __attribute__((ext_vector_type(8)));
typedef __bf16 bf16x4 __attribute__((ext_vector_type(4)));
typedef float  f32x4  __attribute__((ext_vector_type(4)));

#define KDIM 512
#define MDIM 64
#define TDIM 4096
#define BN   128
#define BK   64
#define NTILE (TDIM / BN)   // 32 tiles per batch
#define KITER (KDIM / BK)   // 8

// LDS byte layout
#define SA_OFF   0        // text tile  [64][64]  bf16, swizzled: 8192 B
#define SB_OFF   8192     // audio tile [128][64] bf16, swizzled: 16384 B
#define INVT_OFF 24576    // 64 floats
#define INVA_OFF 24832    // 128 floats
#define LDS_BYTES 25344

// ---- macros (not lambdas-with-pointer-args) so every register-array index
// ---- is compile-time static after unrolling (rule #20: no scratch)

#define LOAD_TILE(PT, PA, K0) do {                                            \
    _Pragma("unroll")                                                         \
    for (int j = 0; j < 4; ++j)                                               \
        PT[j] = *reinterpret_cast<const f32x4*>(                              \
            tBase + (size_t)(j * 16 + r0) * KDIM + (K0) + c4 * 4);            \
    _Pragma("unroll")                                                         \
    for (int j = 0; j < 8; ++j)                                               \
        PA[j] = *reinterpret_cast<const f32x4*>(                              \
            aBase + (size_t)(j * 16 + r0) * KDIM + (K0) + c4 * 4);            \
} while (0)

#define STORE_TILE(PT, PA) do {                                               \
    _Pragma("unroll")                                                         \
    for (int j = 0; j < 4; ++j) {                                             \
        f32x4 v = PT[j];                                                      \
        ssT[j] += v.x * v.x + v.y * v.y + v.z * v.z + v.w * v.w;              \
        bf16x4 q = { (bf16)v.x, (bf16)v.y, (bf16)v.z, (bf16)v.w };            \
        const int row = j * 16 + r0;                                          \
        const int off = SA_OFF + row * 128 + ((c4 * 8) ^ ((row & 7) << 4));   \
        *reinterpret_cast<unsigned long long*>(lds + off) =                   \
            __builtin_bit_cast(unsigned long long, q);                        \
    }                                                                         \
    _Pragma("unroll")                                                         \
    for (int j = 0; j < 8; ++j) {                                             \
        f32x4 v = PA[j];                                                      \
        ssA[j] += v.x * v.x + v.y * v.y + v.z * v.z + v.w * v.w;              \
        bf16x4 q = { (bf16)v.x, (bf16)v.y, (bf16)v.z, (bf16)v.w };            \
        const int row = j * 16 + r0;                                          \
        const int off = SB_OFF + row * 128 + ((c4 * 8) ^ ((row & 7) << 4));   \
        *reinterpret_cast<unsigned long long*>(lds + off) =                   \
            __builtin_bit_cast(unsigned long long, q);                        \
    }                                                                         \
} while (0)

#define MFMA_PHASE() do {                                                     \
    _Pragma("unroll")                                                         \
    for (int kk = 0; kk < 2; ++kk) {                                          \
        const int kbyte = kk * 64 + kgrp * 16;                                \
        bf16x8 afrag[4], bfrag[2];                                            \
        _Pragma("unroll")                                                     \
        for (int mi = 0; mi < 4; ++mi) {                                      \
            const int row = mi * 16 + frow;                                   \
            afrag[mi] = *reinterpret_cast<const bf16x8*>(                     \
                lds + SA_OFF + row * 128 + (kbyte ^ ((row & 7) << 4)));       \
        }                                                                     \
        _Pragma("unroll")                                                     \
        for (int ni = 0; ni < 2; ++ni) {                                      \
            const int trow = wave * 32 + ni * 16 + frow;                      \
            bfrag[ni] = *reinterpret_cast<const bf16x8*>(                     \
                lds + SB_OFF + trow * 128 + (kbyte ^ ((trow & 7) << 4)));     \
        }                                                                     \
        _Pragma("unroll")                                                     \
        for (int mi = 0; mi < 4; ++mi)                                        \
            _Pragma("unroll")                                                 \
            for (int ni = 0; ni < 2; ++ni)                                    \
                asm volatile("v_mfma_f32_16x16x32_bf16 %0, %1, %2, %0"        \
                             : "+v"(acc[mi][ni])                              \
                             : "v"(afrag[mi]), "v"(bfrag[ni]));               \
    }                                                                         \
} while (0)

__global__ __launch_bounds__(256, 2)
void expnegl2_fused_kernel(const float* __restrict__ audio,
                           const float* __restrict__ text,
                           float* __restrict__ out)
{
    __shared__ __attribute__((aligned(16))) unsigned char lds[LDS_BYTES];

    const int tid  = threadIdx.x;

    // XCD swizzle (kept: free; text L2 locality even if L3 masks it at HBM)
    const int linear = blockIdx.x;
    const int cpx    = gridDim.x >> 3;
    const int wg     = (linear & 7) * cpx + (linear >> 3);
    const int b      = wg / NTILE;
    const int t0     = (wg % NTILE) * BN;

    const int c4   = tid & 15;
    const int r0   = tid >> 4;
    const int lane = tid & 63;
    const int wave = tid >> 6;

    const float* aBase = audio + ((size_t)b * TDIM + t0) * KDIM;
    const float* tBase = text  + (size_t)b * MDIM * KDIM;

    f32x4 acc[4][2];
    #pragma unroll
    for (int i = 0; i < 4; ++i)
        #pragma unroll
        for (int j = 0; j < 2; ++j)
            acc[i][j] = (f32x4){0.f, 0.f, 0.f, 0.f};

    float ssA[8], ssT[4];
    #pragma unroll
    for (int j = 0; j < 8; ++j) ssA[j] = 0.f;
    #pragma unroll
    for (int j = 0; j < 4; ++j) ssT[j] = 0.f;

    const int frow = lane & 15;
    const int kgrp = lane >> 4;

    // 2-deep register prefetch: while tile k is consumed, tile k+1's loads
    // (issued a FULL iteration earlier, >=1200cyc cover > ~900cyc HBM miss)
    // are in flight -> counted vmcnt wait is zero-stall, HBM never idles.
    f32x4 pT0[4], pA0[8], pT1[4], pA1[8];

    LOAD_TILE(pT0, pA0, 0);
    LOAD_TILE(pT1, pA1, BK);

    #pragma unroll
    for (int ki = 0; ki < KITER; ki += 2) {
        // ---- even sub-iter: consume set0 (tile ki), refill set0 with ki+2
        STORE_TILE(pT0, pA0);                    // vmcnt waits only set0
        if (ki + 2 < KITER) LOAD_TILE(pT0, pA0, (ki + 2) * BK);
        __syncthreads();                         // tile ki visible
        MFMA_PHASE();
        __syncthreads();                         // LDS reusable

        // ---- odd sub-iter: consume set1 (tile ki+1), refill with ki+3
        STORE_TILE(pT1, pA1);
        if (ki + 3 < KITER) LOAD_TILE(pT1, pA1, (ki + 3) * BK);
        __syncthreads();
        MFMA_PHASE();
        __syncthreads();
    }

    // ---- reduce sum-of-squares across the 16 lanes sharing a row ----
    #pragma unroll
    for (int j = 0; j < 4; ++j) {
        float s = ssT[j];
        s += __shfl_xor(s, 1); s += __shfl_xor(s, 2);
        s += __shfl_xor(s, 4); s += __shfl_xor(s, 8);
        ssT[j] = s;
    }
    #pragma unroll
    for (int j = 0; j < 8; ++j) {
        float s = ssA[j];
        s += __shfl_xor(s, 1); s += __shfl_xor(s, 2);
        s += __shfl_xor(s, 4); s += __shfl_xor(s, 8);
        ssA[j] = s;
    }
    float* invT = reinterpret_cast<float*>(lds + INVT_OFF);
    float* invA = reinterpret_cast<float*>(lds + INVA_OFF);
    if (c4 == 0) {
        #pragma unroll
        for (int j = 0; j < 4; ++j)
            invT[j * 16 + r0] = 1.f / fmaxf(sqrtf(ssT[j]), 1e-12f);
        #pragma unroll
        for (int j = 0; j < 8; ++j)
            invA[j * 16 + r0] = 1.f / fmaxf(sqrtf(ssA[j]), 1e-12f);
    }
    __syncthreads();

    // ---- epilogue ----
    float* obase = out + (size_t)b * MDIM * TDIM + t0;
    #pragma unroll
    for (int ni = 0; ni < 2; ++ni) {
        const int cl = wave * 32 + ni * 16 + frow;
        const float iA = invA[cl];
        #pragma unroll
        for (int mi = 0; mi < 4; ++mi) {
            #pragma unroll
            for (int j = 0; j < 4; ++j) {
                const int m = mi * 16 + kgrp * 4 + j;
                const float dotn = acc[mi][ni][j] * invT[m] * iA;
                const float d2 = fmaxf(2.f - 2.f * dotn, 1e-12f);
                obase[(size_t)m * TDIM + cl] = __expf(-sqrtf(d2));
            }
        }
    }
}

extern "C" void kernel_launch(void* const* d_in, const int* in_sizes, int n_in,
                              void* d_out, int out_size, void* d_ws, size_t ws_size,
                              hipStream_t stream) {
    const float* audio = (const float*)d_in[0];
    const float* text  = (const float*)d_in[1];
    float* out = (float*)d_out;

    const int B = in_sizes[0] / (TDIM * KDIM);   // 32
    dim3 grid(B * NTILE);                        // 1024
    expnegl2_fused_kernel<<<grid, 256, 0, stream>>>(audio, text, out);
}